// Round 1
// baseline (291.843 us; speedup 1.0000x reference)
//
#include <hip/hip_runtime.h>
#include <math.h>

// Problem constants: B=32, C=64, H=128, W=128
#define HW 16384     // 128*128 plane elements
#define NPLANE 2048  // B*C planes

// 128-point WHT across a wave: lane holds elements (lane, lane+64) of the row.
// Stage bit6 is in-lane; bits 0..5 are shfl_xor with masks 1..32.
__device__ __forceinline__ void wht128(float& t0, float& t1, int lane) {
    // bit 6 (pair (i, i+64)) — local
    float a = t0 + t1;
    float b = t0 - t1;
    t0 = a; t1 = b;
    #pragma unroll
    for (int m = 1; m <= 32; m <<= 1) {
        float o0 = __shfl_xor(t0, m, 64);
        float o1 = __shfl_xor(t1, m, 64);
        bool hi = (lane & m) != 0;
        t0 = hi ? (o0 - t0) : (t0 + o0);
        t1 = hi ? (o1 - t1) : (t1 + o1);
    }
}

// Forward 2D WHT of one 128x128 plane per workgroup. src -> dst (dst may be a
// different buffer). LDS layout XOR-swizzled: element (r, w) stored at
// r*128 + (w ^ (r & 63))  (bit6 of w preserved) -> all accesses <=2-way banks.
__global__ __launch_bounds__(512) void k_wht2d_fwd(const float* __restrict__ x,
                                                   float* __restrict__ out) {
    __shared__ float lds[128 * 128];  // 64 KiB
    const int tid  = threadIdx.x;
    const int lane = tid & 63;
    const int wid  = tid >> 6;  // 0..7
    const size_t plane = (size_t)blockIdx.x * HW;
    const float* src = x + plane;
    float* dst = out + plane;

    // Phase 1: row WHT (along w), write swizzled to LDS
    #pragma unroll
    for (int k = 0; k < 16; ++k) {
        int r = wid * 16 + k;
        float t0 = src[r * 128 + lane];
        float t1 = src[r * 128 + lane + 64];
        wht128(t0, t1, lane);
        int col = lane ^ (r & 63);
        lds[r * 128 + col] = t0;
        lds[r * 128 + col + 64] = t1;
    }
    __syncthreads();

    // Phase 2: column WHT (along h), in LDS. Lane i covers h=i and h=i+64.
    #pragma unroll
    for (int k = 0; k < 16; ++k) {
        int c0 = wid * 16 + k;
        int a0 = lane * 128 + (c0 ^ lane);          // h = lane   : (h&63)=lane
        int a1 = (lane + 64) * 128 + (c0 ^ lane);   // h = lane+64: (h&63)=lane
        float t0 = lds[a0];
        float t1 = lds[a1];
        wht128(t0, t1, lane);
        lds[a0] = t0;
        lds[a1] = t1;
    }
    __syncthreads();

    // Phase 3: coalesced row write-out
    #pragma unroll
    for (int k = 0; k < 16; ++k) {
        int r = wid * 16 + k;
        int col = lane ^ (r & 63);
        dst[r * 128 + lane]      = lds[r * 128 + col];
        dst[r * 128 + lane + 64] = lds[r * 128 + col + 64];
    }
}

// Inverse 2D WHT (same transform) + /16384 + residual x. In-place on buf.
__global__ __launch_bounds__(512) void k_wht2d_inv(float* __restrict__ buf,
                                                   const float* __restrict__ x) {
    __shared__ float lds[128 * 128];
    const int tid  = threadIdx.x;
    const int lane = tid & 63;
    const int wid  = tid >> 6;
    const size_t plane = (size_t)blockIdx.x * HW;
    float* dst = buf + plane;
    const float* xr = x + plane;

    #pragma unroll
    for (int k = 0; k < 16; ++k) {
        int r = wid * 16 + k;
        float t0 = dst[r * 128 + lane];
        float t1 = dst[r * 128 + lane + 64];
        wht128(t0, t1, lane);
        int col = lane ^ (r & 63);
        lds[r * 128 + col] = t0;
        lds[r * 128 + col + 64] = t1;
    }
    __syncthreads();

    #pragma unroll
    for (int k = 0; k < 16; ++k) {
        int c0 = wid * 16 + k;
        int a0 = lane * 128 + (c0 ^ lane);
        int a1 = (lane + 64) * 128 + (c0 ^ lane);
        float t0 = lds[a0];
        float t1 = lds[a1];
        wht128(t0, t1, lane);
        lds[a0] = t0;
        lds[a1] = t1;
    }
    __syncthreads();

    const float s = 1.0f / 16384.0f;
    #pragma unroll
    for (int k = 0; k < 16; ++k) {
        int r = wid * 16 + k;
        int col = lane ^ (r & 63);
        dst[r * 128 + lane]      = lds[r * 128 + col]      * s + xr[r * 128 + lane];
        dst[r * 128 + lane + 64] = lds[r * 128 + col + 64] * s + xr[r * 128 + lane + 64];
    }
}

// Channel mix + soft-threshold, in-place on buf (layout [b][c][hw]).
// Thread t handles one (b, hw) column: reads f2[c][hw] for all c, accumulates
// all 64 outputs, then overwrites f6[o][hw]. W held transposed in LDS so the
// inner loop reads 4 weights per ds_read_b128 broadcast.
__global__ __launch_bounds__(256) void k_mix(float* __restrict__ buf,
                                             const float* __restrict__ W,
                                             const float* __restrict__ v,
                                             const float* __restrict__ T) {
    __shared__ float Wt[64 * 64];  // Wt[c][o] = W[o][c], 16 KiB
    const int tid = threadIdx.x;
    #pragma unroll
    for (int k = 0; k < 16; ++k) {
        int idx = k * 256 + tid;          // idx = o*64 + c
        Wt[(idx & 63) * 64 + (idx >> 6)] = W[idx];
    }
    __syncthreads();

    const int b  = blockIdx.x >> 6;
    const int hw = ((blockIdx.x & 63) << 8) + tid;   // 0..16383
    float* base = buf + (size_t)b * 64 * HW + hw;

    const float vp = v[hw];
    float acc[64];
    #pragma unroll
    for (int o = 0; o < 64; ++o) acc[o] = 0.0f;

    #pragma unroll 4
    for (int c = 0; c < 64; ++c) {
        float xv = base[(size_t)c * HW] * vp;
        const float4* wrow = reinterpret_cast<const float4*>(&Wt[c * 64]);
        #pragma unroll
        for (int q = 0; q < 16; ++q) {
            float4 w4 = wrow[q];  // uniform address -> LDS broadcast b128
            acc[4 * q + 0] += w4.x * xv;
            acc[4 * q + 1] += w4.y * xv;
            acc[4 * q + 2] += w4.z * xv;
            acc[4 * q + 3] += w4.w * xv;
        }
    }

    const float Tp = fmaxf(T[hw], 0.0f);  // relu(T)
    #pragma unroll
    for (int o = 0; o < 64; ++o) {
        float val = acc[o];
        float mag = fmaxf(fabsf(val) - Tp, 0.0f);
        base[(size_t)o * HW] = copysignf(mag, val);
    }
}

extern "C" void kernel_launch(void* const* d_in, const int* in_sizes, int n_in,
                              void* d_out, int out_size, void* d_ws, size_t ws_size,
                              hipStream_t stream) {
    const float* x = (const float*)d_in[0];
    const float* W = (const float*)d_in[1];
    const float* v = (const float*)d_in[2];
    const float* T = (const float*)d_in[3];
    float* out = (float*)d_out;

    // f2 = WHT2D(x) -> d_out
    k_wht2d_fwd<<<NPLANE, 512, 0, stream>>>(x, out);
    // f6 = soft_threshold(W @ (v .* f2), T) -> d_out (in place)
    k_mix<<<32 * 64, 256, 0, stream>>>(out, W, v, T);
    // y = WHT2D(f6)/16384 + x -> d_out (in place)
    k_wht2d_inv<<<NPLANE, 512, 0, stream>>>(out, x);
}

// Round 2
// 276.654 us; speedup vs baseline: 1.0549x; 1.0549x over previous
//
#include <hip/hip_runtime.h>
#include <math.h>

// Problem constants: B=32, C=64, H=128, W=128
#define HW 16384     // 128*128 plane elements
#define NPLANE 2048  // B*C planes

// 128-point WHT across a wave: lane holds elements (lane, lane+64) of the row.
// Stage bit6 is in-lane; bits 0..5 are shfl_xor with masks 1..32.
__device__ __forceinline__ void wht128(float& t0, float& t1, int lane) {
    float a = t0 + t1;
    float b = t0 - t1;
    t0 = a; t1 = b;
    #pragma unroll
    for (int m = 1; m <= 32; m <<= 1) {
        float o0 = __shfl_xor(t0, m, 64);
        float o1 = __shfl_xor(t1, m, 64);
        bool hi = (lane & m) != 0;
        t0 = hi ? (o0 - t0) : (t0 + o0);
        t1 = hi ? (o1 - t1) : (t1 + o1);
    }
}

// Forward 2D WHT of one 128x128 plane per workgroup. LDS XOR-swizzled:
// element (r, w) stored at r*128 + (w ^ (r & 63)) -> <=2-way banks everywhere.
__global__ __launch_bounds__(512) void k_wht2d_fwd(const float* __restrict__ x,
                                                   float* __restrict__ out) {
    __shared__ float lds[128 * 128];  // 64 KiB
    const int tid  = threadIdx.x;
    const int lane = tid & 63;
    const int wid  = tid >> 6;  // 0..7
    const size_t plane = (size_t)blockIdx.x * HW;
    const float* src = x + plane;
    float* dst = out + plane;

    #pragma unroll
    for (int k = 0; k < 16; ++k) {
        int r = wid * 16 + k;
        float t0 = src[r * 128 + lane];
        float t1 = src[r * 128 + lane + 64];
        wht128(t0, t1, lane);
        int col = lane ^ (r & 63);
        lds[r * 128 + col] = t0;
        lds[r * 128 + col + 64] = t1;
    }
    __syncthreads();

    #pragma unroll
    for (int k = 0; k < 16; ++k) {
        int c0 = wid * 16 + k;
        int a0 = lane * 128 + (c0 ^ lane);
        int a1 = (lane + 64) * 128 + (c0 ^ lane);
        float t0 = lds[a0];
        float t1 = lds[a1];
        wht128(t0, t1, lane);
        lds[a0] = t0;
        lds[a1] = t1;
    }
    __syncthreads();

    #pragma unroll
    for (int k = 0; k < 16; ++k) {
        int r = wid * 16 + k;
        int col = lane ^ (r & 63);
        dst[r * 128 + lane]      = lds[r * 128 + col];
        dst[r * 128 + lane + 64] = lds[r * 128 + col + 64];
    }
}

// Inverse 2D WHT + /16384 + residual x. In-place on buf.
__global__ __launch_bounds__(512) void k_wht2d_inv(float* __restrict__ buf,
                                                   const float* __restrict__ x) {
    __shared__ float lds[128 * 128];
    const int tid  = threadIdx.x;
    const int lane = tid & 63;
    const int wid  = tid >> 6;
    const size_t plane = (size_t)blockIdx.x * HW;
    float* dst = buf + plane;
    const float* xr = x + plane;

    #pragma unroll
    for (int k = 0; k < 16; ++k) {
        int r = wid * 16 + k;
        float t0 = dst[r * 128 + lane];
        float t1 = dst[r * 128 + lane + 64];
        wht128(t0, t1, lane);
        int col = lane ^ (r & 63);
        lds[r * 128 + col] = t0;
        lds[r * 128 + col + 64] = t1;
    }
    __syncthreads();

    #pragma unroll
    for (int k = 0; k < 16; ++k) {
        int c0 = wid * 16 + k;
        int a0 = lane * 128 + (c0 ^ lane);
        int a1 = (lane + 64) * 128 + (c0 ^ lane);
        float t0 = lds[a0];
        float t1 = lds[a1];
        wht128(t0, t1, lane);
        lds[a0] = t0;
        lds[a1] = t1;
    }
    __syncthreads();

    const float s = 1.0f / 16384.0f;
    #pragma unroll
    for (int k = 0; k < 16; ++k) {
        int r = wid * 16 + k;
        int col = lane ^ (r & 63);
        dst[r * 128 + lane]      = lds[r * 128 + col]      * s + xr[r * 128 + lane];
        dst[r * 128 + lane + 64] = lds[r * 128 + col + 64] * s + xr[r * 128 + lane + 64];
    }
}

// Tiny transpose: Wt[c][o] = W[o][c]  (64x64), into d_ws.
__global__ __launch_bounds__(256) void k_wtrans(const float* __restrict__ W,
                                                float* __restrict__ Wt) {
    int i = blockIdx.x * 256 + threadIdx.x;   // i = o*64 + c
    Wt[(i & 63) * 64 + (i >> 6)] = W[i];
}

// Channel mix + soft-threshold, in-place on buf (layout [b][c][hw]).
// Each thread owns one (b, hw-pair): reads f2[c][hw..hw+1] for all c,
// accumulates all 64 outputs into 128 VGPRs, overwrites f6[o][hw..hw+1].
// Weights read at wave-uniform addresses from pre-transposed Wt -> scalar
// loads (SGPR), zero LDS usage.
__global__ __launch_bounds__(256) void k_mix(float* __restrict__ buf,
                                             const float* __restrict__ Wt,
                                             const float* __restrict__ v,
                                             const float* __restrict__ T) {
    const int gid = blockIdx.x * 256 + threadIdx.x;  // 0 .. 262143
    const int b   = gid >> 13;                        // 8192 pairs per batch
    const int hw  = (gid & 8191) * 2;
    float* base = buf + (size_t)b * 64 * HW + hw;

    const float2 vp = *reinterpret_cast<const float2*>(v + hw);
    float acc0[64], acc1[64];
    #pragma unroll
    for (int o = 0; o < 64; ++o) { acc0[o] = 0.0f; acc1[o] = 0.0f; }

    #pragma unroll 4
    for (int c = 0; c < 64; ++c) {
        float2 xv = *reinterpret_cast<const float2*>(base + (size_t)c * HW);
        float x0 = xv.x * vp.x;
        float x1 = xv.y * vp.y;
        const float4* wrow = reinterpret_cast<const float4*>(Wt + c * 64);
        #pragma unroll
        for (int q = 0; q < 16; ++q) {
            float4 w4 = wrow[q];  // wave-uniform address -> s_load_dwordx4
            acc0[4 * q + 0] += w4.x * x0;  acc1[4 * q + 0] += w4.x * x1;
            acc0[4 * q + 1] += w4.y * x0;  acc1[4 * q + 1] += w4.y * x1;
            acc0[4 * q + 2] += w4.z * x0;  acc1[4 * q + 2] += w4.z * x1;
            acc0[4 * q + 3] += w4.w * x0;  acc1[4 * q + 3] += w4.w * x1;
        }
    }

    const float2 Tv = *reinterpret_cast<const float2*>(T + hw);
    const float Tp0 = fmaxf(Tv.x, 0.0f);
    const float Tp1 = fmaxf(Tv.y, 0.0f);
    #pragma unroll
    for (int o = 0; o < 64; ++o) {
        float m0 = fmaxf(fabsf(acc0[o]) - Tp0, 0.0f);
        float m1 = fmaxf(fabsf(acc1[o]) - Tp1, 0.0f);
        float2 r;
        r.x = copysignf(m0, acc0[o]);
        r.y = copysignf(m1, acc1[o]);
        *reinterpret_cast<float2*>(base + (size_t)o * HW) = r;
    }
}

extern "C" void kernel_launch(void* const* d_in, const int* in_sizes, int n_in,
                              void* d_out, int out_size, void* d_ws, size_t ws_size,
                              hipStream_t stream) {
    const float* x = (const float*)d_in[0];
    const float* W = (const float*)d_in[1];
    const float* v = (const float*)d_in[2];
    const float* T = (const float*)d_in[3];
    float* out = (float*)d_out;
    float* Wt  = (float*)d_ws;   // 16 KiB

    k_wtrans<<<16, 256, 0, stream>>>(W, Wt);
    // f2 = WHT2D(x) -> d_out
    k_wht2d_fwd<<<NPLANE, 512, 0, stream>>>(x, out);
    // f6 = soft_threshold(W @ (v .* f2), T) -> d_out (in place)
    k_mix<<<1024, 256, 0, stream>>>(out, Wt, v, T);
    // y = WHT2D(f6)/16384 + x -> d_out (in place)
    k_wht2d_inv<<<NPLANE, 512, 0, stream>>>(out, x);
}

// Round 3
// 201.287 us; speedup vs baseline: 1.4499x; 1.3744x over previous
//
#include <hip/hip_runtime.h>
#include <math.h>

// Problem constants: B=32, C=64, H=128, W=128
#define HW 16384     // 128*128 plane elements
#define NPLANE 2048  // B*C planes

// ---------------------------------------------------------------------------
// 2D WHT(128x128) == 1D WHT(16384) over the row-major flattened plane
// (H128 (x) H128 = H2^(x)14). 256 threads/plane, 64 elems/thread (16 float4).
// Phase A: 6 stages in-register (bits {0,1} in-quad, {8..11} across regs).
// Phase B: 4 stages (bits {2,3,4,12}) after LDS transpose.
// Phase C: 4 stages (bits {5,6,7,13}) after LDS transpose.
// All LDS accesses at phys = logical ^ (((logical>>5)&7)<<2) -> 2-way banks.
// ---------------------------------------------------------------------------

__device__ __forceinline__ void bf_quad(float4& a) {
    // logical bit 0: pairs (x,y),(z,w); then bit 1: pairs (.,.)
    float s0 = a.x + a.y, d0 = a.x - a.y;
    float s1 = a.z + a.w, d1 = a.z - a.w;
    a.x = s0 + s1; a.y = d0 + d1; a.z = s0 - s1; a.w = d0 - d1;
}

__device__ __forceinline__ void bf_pair(float4& a, float4& b) {
    float4 s, d;
    s.x = a.x + b.x; s.y = a.y + b.y; s.z = a.z + b.z; s.w = a.w + b.w;
    d.x = a.x - b.x; d.y = a.y - b.y; d.z = a.z - b.z; d.w = a.w - b.w;
    a = s; b = d;
}

// 4 butterfly stages across the 16-register index (masks 1,2,4,8).
__device__ __forceinline__ void bf_regs4(float4* r) {
    #pragma unroll
    for (int m = 1; m <= 8; m <<= 1) {
        #pragma unroll
        for (int j = 0; j < 16; ++j) {
            if ((j & m) == 0) bf_pair(r[j], r[j | m]);
        }
    }
}

// Shared body: loads plane from src (coalesced), full 14-stage WHT into r[],
// leaves results with logical index i(j,q) = q + (l&7)*4 + (j&7)*32
//   + (l>>3)*256 + w*2048 + (j>>3)*8192   (q = component of float4).
__device__ __forceinline__ void wht16384(const float* __restrict__ src,
                                         float* __restrict__ lds,
                                         float4 (&r)[16],
                                         int l, int w) {
    const int l7 = l & 7, l3 = l >> 3;

    // ---- Phase A: load + bits {0,1,8,9,10,11} ----
    const int loadBase = w * 4096 + l * 4;
    #pragma unroll
    for (int j = 0; j < 16; ++j)
        r[j] = *reinterpret_cast<const float4*>(src + loadBase + j * 256);

    #pragma unroll
    for (int j = 0; j < 16; ++j) bf_quad(r[j]);
    bf_regs4(r);  // bits 8..11

    // store: logical a = w*4096 + j*256 + l*4 ; swizzle bits2-4 ^= (l>>3)
    const int sA = w * 4096 + ((l7 ^ l3) << 2) + (l3 << 5);
    #pragma unroll
    for (int j = 0; j < 16; ++j)
        *reinterpret_cast<float4*>(lds + sA + j * 256) = r[j];
    __syncthreads();

    // ---- Phase B: bits {2,3,4,12} ----
    // fixed: bits5-7=l7, bits8-10=l3, bit11=w&1, bit13=w>>1
    // logical a = q + (j&7)*4 + l7*32 + l3*256 + (w&1)*2048 + (j>>3)*4096
    //           + (w>>1)*8192 ; swizzle bits2-4 ^= l7
    const int bB = (l7 << 5) + (l3 << 8) + ((w & 1) << 11) + ((w >> 1) << 13);
    #pragma unroll
    for (int j = 0; j < 16; ++j)
        r[j] = *reinterpret_cast<const float4*>(
            lds + bB + (((j & 7) ^ l7) << 2) + ((j >> 3) << 12));
    bf_regs4(r);  // bits 2,3,4,12
    #pragma unroll
    for (int j = 0; j < 16; ++j)
        *reinterpret_cast<float4*>(
            lds + bB + (((j & 7) ^ l7) << 2) + ((j >> 3) << 12)) = r[j];
    __syncthreads();

    // ---- Phase C: bits {5,6,7,13} ----
    // fixed: bits2-4=l7, bits8-10=l3, bits11-12=w
    // logical a = q + l7*4 + (j&7)*32 + l3*256 + w*2048 + (j>>3)*8192
    // swizzle bits2-4 ^= (j&7)
    const int bC = (l3 << 8) + (w << 11);
    #pragma unroll
    for (int j = 0; j < 16; ++j)
        r[j] = *reinterpret_cast<const float4*>(
            lds + bC + ((l7 ^ (j & 7)) << 2) + ((j & 7) << 5) + ((j >> 3) << 13));
    bf_regs4(r);  // bits 5,6,7,13
}

__global__ __launch_bounds__(256) void k_wht2d_fwd(const float* __restrict__ x,
                                                   float* __restrict__ out) {
    __shared__ float lds[HW];  // 64 KiB
    const int t = threadIdx.x;
    const int l = t & 63, w = t >> 6;
    const int l7 = l & 7, l3 = l >> 3;
    const size_t plane = (size_t)blockIdx.x * HW;

    float4 r[16];
    wht16384(x + plane, lds, r, l, w);

    float* dst = out + plane;
    const int oB = (l7 << 2) + (l3 << 8) + (w << 11);
    #pragma unroll
    for (int j = 0; j < 16; ++j)
        *reinterpret_cast<float4*>(dst + oB + ((j & 7) << 5) + ((j >> 3) << 13)) = r[j];
}

// Inverse: same transform on buf, then *1/16384 + x, in-place on buf.
__global__ __launch_bounds__(256) void k_wht2d_inv(float* __restrict__ buf,
                                                   const float* __restrict__ x) {
    __shared__ float lds[HW];
    const int t = threadIdx.x;
    const int l = t & 63, w = t >> 6;
    const int l7 = l & 7, l3 = l >> 3;
    const size_t plane = (size_t)blockIdx.x * HW;

    float4 r[16];
    wht16384(buf + plane, lds, r, l, w);

    float* dst = buf + plane;
    const float* xr = x + plane;
    const float s = 1.0f / 16384.0f;
    const int oB = (l7 << 2) + (l3 << 8) + (w << 11);
    #pragma unroll
    for (int j = 0; j < 16; ++j) {
        const int off = oB + ((j & 7) << 5) + ((j >> 3) << 13);
        float4 xv = *reinterpret_cast<const float4*>(xr + off);
        float4 o;
        o.x = r[j].x * s + xv.x;
        o.y = r[j].y * s + xv.y;
        o.z = r[j].z * s + xv.z;
        o.w = r[j].w * s + xv.w;
        *reinterpret_cast<float4*>(dst + off) = o;
    }
}

// Tiny transpose: Wt[c][o] = W[o][c]  (64x64), into d_ws.
__global__ __launch_bounds__(256) void k_wtrans(const float* __restrict__ W,
                                                float* __restrict__ Wt) {
    int i = blockIdx.x * 256 + threadIdx.x;   // i = o*64 + c
    Wt[(i & 63) * 64 + (i >> 6)] = W[i];
}

// Channel mix + soft-threshold, in-place on buf (layout [b][c][hw]).
// Each thread owns one (b, hw-pair): reads f2[c][hw..hw+1] for all c,
// accumulates all 64 outputs, overwrites f6[o][hw..hw+1]. Weights read at
// wave-uniform addresses from pre-transposed Wt -> scalar loads, zero LDS.
__global__ __launch_bounds__(256) void k_mix(float* __restrict__ buf,
                                             const float* __restrict__ Wt,
                                             const float* __restrict__ v,
                                             const float* __restrict__ T) {
    const int gid = blockIdx.x * 256 + threadIdx.x;  // 0 .. 262143
    const int b   = gid >> 13;                        // 8192 pairs per batch
    const int hw  = (gid & 8191) * 2;
    float* base = buf + (size_t)b * 64 * HW + hw;

    const float2 vp = *reinterpret_cast<const float2*>(v + hw);
    float acc0[64], acc1[64];
    #pragma unroll
    for (int o = 0; o < 64; ++o) { acc0[o] = 0.0f; acc1[o] = 0.0f; }

    #pragma unroll 4
    for (int c = 0; c < 64; ++c) {
        float2 xv = *reinterpret_cast<const float2*>(base + (size_t)c * HW);
        float x0 = xv.x * vp.x;
        float x1 = xv.y * vp.y;
        const float4* wrow = reinterpret_cast<const float4*>(Wt + c * 64);
        #pragma unroll
        for (int q = 0; q < 16; ++q) {
            float4 w4 = wrow[q];  // wave-uniform address -> s_load_dwordx4
            acc0[4 * q + 0] += w4.x * x0;  acc1[4 * q + 0] += w4.x * x1;
            acc0[4 * q + 1] += w4.y * x0;  acc1[4 * q + 1] += w4.y * x1;
            acc0[4 * q + 2] += w4.z * x0;  acc1[4 * q + 2] += w4.z * x1;
            acc0[4 * q + 3] += w4.w * x0;  acc1[4 * q + 3] += w4.w * x1;
        }
    }

    const float2 Tv = *reinterpret_cast<const float2*>(T + hw);
    const float Tp0 = fmaxf(Tv.x, 0.0f);
    const float Tp1 = fmaxf(Tv.y, 0.0f);
    #pragma unroll
    for (int o = 0; o < 64; ++o) {
        float m0 = fmaxf(fabsf(acc0[o]) - Tp0, 0.0f);
        float m1 = fmaxf(fabsf(acc1[o]) - Tp1, 0.0f);
        float2 r;
        r.x = copysignf(m0, acc0[o]);
        r.y = copysignf(m1, acc1[o]);
        *reinterpret_cast<float2*>(base + (size_t)o * HW) = r;
    }
}

extern "C" void kernel_launch(void* const* d_in, const int* in_sizes, int n_in,
                              void* d_out, int out_size, void* d_ws, size_t ws_size,
                              hipStream_t stream) {
    const float* x = (const float*)d_in[0];
    const float* W = (const float*)d_in[1];
    const float* v = (const float*)d_in[2];
    const float* T = (const float*)d_in[3];
    float* out = (float*)d_out;
    float* Wt  = (float*)d_ws;   // 16 KiB

    k_wtrans<<<16, 256, 0, stream>>>(W, Wt);
    // f2 = WHT2D(x) -> d_out
    k_wht2d_fwd<<<NPLANE, 256, 0, stream>>>(x, out);
    // f6 = soft_threshold(W @ (v .* f2), T) -> d_out (in place)
    k_mix<<<1024, 256, 0, stream>>>(out, Wt, v, T);
    // y = WHT2D(f6)/16384 + x -> d_out (in place)
    k_wht2d_inv<<<NPLANE, 256, 0, stream>>>(out, x);
}

// Round 4
// 150.377 us; speedup vs baseline: 1.9407x; 1.3386x over previous
//
#include <hip/hip_runtime.h>
#include <math.h>

// Problem constants: B=32, C=64, H=128, W=128
#define HW 16384     // 128*128 plane elements
#define NPLANE 2048  // B*C planes

typedef __bf16 bf16x8 __attribute__((ext_vector_type(8)));
typedef float  f32x4  __attribute__((ext_vector_type(4)));

// ---------------------------------------------------------------------------
// 2D WHT(128x128) == 1D WHT(16384) over the row-major flattened plane.
// 256 threads/plane, 64 elems/thread (16 float4), 3 phases, 0 shuffles.
// ---------------------------------------------------------------------------

__device__ __forceinline__ void bf_quad(float4& a) {
    float s0 = a.x + a.y, d0 = a.x - a.y;
    float s1 = a.z + a.w, d1 = a.z - a.w;
    a.x = s0 + s1; a.y = d0 + d1; a.z = s0 - s1; a.w = d0 - d1;
}

__device__ __forceinline__ void bf_pair(float4& a, float4& b) {
    float4 s, d;
    s.x = a.x + b.x; s.y = a.y + b.y; s.z = a.z + b.z; s.w = a.w + b.w;
    d.x = a.x - b.x; d.y = a.y - b.y; d.z = a.z - b.z; d.w = a.w - b.w;
    a = s; b = d;
}

__device__ __forceinline__ void bf_regs4(float4* r) {
    #pragma unroll
    for (int m = 1; m <= 8; m <<= 1) {
        #pragma unroll
        for (int j = 0; j < 16; ++j) {
            if ((j & m) == 0) bf_pair(r[j], r[j | m]);
        }
    }
}

__device__ __forceinline__ void wht16384(const float* __restrict__ src,
                                         float* __restrict__ lds,
                                         float4 (&r)[16],
                                         int l, int w) {
    const int l7 = l & 7, l3 = l >> 3;

    const int loadBase = w * 4096 + l * 4;
    #pragma unroll
    for (int j = 0; j < 16; ++j)
        r[j] = *reinterpret_cast<const float4*>(src + loadBase + j * 256);

    #pragma unroll
    for (int j = 0; j < 16; ++j) bf_quad(r[j]);
    bf_regs4(r);  // bits 8..11

    const int sA = w * 4096 + ((l7 ^ l3) << 2) + (l3 << 5);
    #pragma unroll
    for (int j = 0; j < 16; ++j)
        *reinterpret_cast<float4*>(lds + sA + j * 256) = r[j];
    __syncthreads();

    const int bB = (l7 << 5) + (l3 << 8) + ((w & 1) << 11) + ((w >> 1) << 13);
    #pragma unroll
    for (int j = 0; j < 16; ++j)
        r[j] = *reinterpret_cast<const float4*>(
            lds + bB + (((j & 7) ^ l7) << 2) + ((j >> 3) << 12));
    bf_regs4(r);  // bits 2,3,4,12
    #pragma unroll
    for (int j = 0; j < 16; ++j)
        *reinterpret_cast<float4*>(
            lds + bB + (((j & 7) ^ l7) << 2) + ((j >> 3) << 12)) = r[j];
    __syncthreads();

    const int bC = (l3 << 8) + (w << 11);
    #pragma unroll
    for (int j = 0; j < 16; ++j)
        r[j] = *reinterpret_cast<const float4*>(
            lds + bC + ((l7 ^ (j & 7)) << 2) + ((j & 7) << 5) + ((j >> 3) << 13));
    bf_regs4(r);  // bits 5,6,7,13
}

__global__ __launch_bounds__(256) void k_wht2d_fwd(const float* __restrict__ x,
                                                   float* __restrict__ out) {
    __shared__ float lds[HW];  // 64 KiB
    const int t = threadIdx.x;
    const int l = t & 63, w = t >> 6;
    const int l7 = l & 7, l3 = l >> 3;
    const size_t plane = (size_t)blockIdx.x * HW;

    float4 r[16];
    wht16384(x + plane, lds, r, l, w);

    float* dst = out + plane;
    const int oB = (l7 << 2) + (l3 << 8) + (w << 11);
    #pragma unroll
    for (int j = 0; j < 16; ++j)
        *reinterpret_cast<float4*>(dst + oB + ((j & 7) << 5) + ((j >> 3) << 13)) = r[j];
}

__global__ __launch_bounds__(256) void k_wht2d_inv(float* __restrict__ buf,
                                                   const float* __restrict__ x) {
    __shared__ float lds[HW];
    const int t = threadIdx.x;
    const int l = t & 63, w = t >> 6;
    const int l7 = l & 7, l3 = l >> 3;
    const size_t plane = (size_t)blockIdx.x * HW;

    float4 r[16];
    wht16384(buf + plane, lds, r, l, w);

    float* dst = buf + plane;
    const float* xr = x + plane;
    const float s = 1.0f / 16384.0f;
    const int oB = (l7 << 2) + (l3 << 8) + (w << 11);
    #pragma unroll
    for (int j = 0; j < 16; ++j) {
        const int off = oB + ((j & 7) << 5) + ((j >> 3) << 13);
        float4 xv = *reinterpret_cast<const float4*>(xr + off);
        float4 o;
        o.x = r[j].x * s + xv.x;
        o.y = r[j].y * s + xv.y;
        o.z = r[j].z * s + xv.z;
        o.w = r[j].w * s + xv.w;
        *reinterpret_cast<float4*>(dst + off) = o;
    }
}

// ---------------------------------------------------------------------------
// Channel mix via bf16 MFMA: per b, Out = W(64x64) . (v .* f2)(64 x 16384),
// soft-threshold fused, in-place on buf. Block = 256 thr (4 waves), one b and
// one 128-position tile. W lives in A-fragments (loaded once). LDS tile is
// fp32, XOR-swizzled by (c>>3)&3 so B-frag column reads are 2-way (free).
// mfma_f32_16x16x32_bf16 layouts:
//   A[m][k]: m = lane&15, k = (lane>>4)*8 + j
//   B[k][n]: n = lane&15, k = (lane>>4)*8 + j
//   D[m][n]: n = lane&15, m = (lane>>4)*4 + reg
// ---------------------------------------------------------------------------
__global__ __launch_bounds__(256) void k_mix_mfma(float* __restrict__ buf,
                                                  const float* __restrict__ W,
                                                  const float* __restrict__ v,
                                                  const float* __restrict__ T) {
    __shared__ float Xs[64 * 128];  // 32 KiB
    const int t = threadIdx.x;
    const int l = t & 63, w = t >> 6;
    const int b  = blockIdx.x >> 7;          // 0..31
    const int p0 = (blockIdx.x & 127) << 7;  // tile * 128
    float* base = buf + (size_t)b * 64 * HW + p0;

    // --- A-fragments: W[o][c], loaded once ---
    bf16x8 A[4][2];
    {
        const int row = l & 15;
        const int kc  = (l >> 4) * 8;
        #pragma unroll
        for (int mt = 0; mt < 4; ++mt) {
            const float* wr = W + (mt * 16 + row) * 64 + kc;
            #pragma unroll
            for (int ks = 0; ks < 2; ++ks) {
                float4 w0 = *reinterpret_cast<const float4*>(wr + ks * 32);
                float4 w1 = *reinterpret_cast<const float4*>(wr + ks * 32 + 4);
                bf16x8 a;
                a[0] = (__bf16)w0.x; a[1] = (__bf16)w0.y;
                a[2] = (__bf16)w0.z; a[3] = (__bf16)w0.w;
                a[4] = (__bf16)w1.x; a[5] = (__bf16)w1.y;
                a[6] = (__bf16)w1.z; a[7] = (__bf16)w1.w;
                A[mt][ks] = a;
            }
        }
    }

    // --- Stage v .* f2 tile [64 c][128 p] fp32 into swizzled LDS ---
    #pragma unroll
    for (int i = 0; i < 8; ++i) {
        const int d  = i * 1024 + t * 4;   // dword index in tile
        const int c  = d >> 7;
        const int pq = d & 127;            // quad-aligned p
        float4 xv = *reinterpret_cast<const float4*>(base + (size_t)c * HW + pq);
        float4 vv = *reinterpret_cast<const float4*>(v + p0 + pq);
        float4 r;
        r.x = xv.x * vv.x; r.y = xv.y * vv.y;
        r.z = xv.z * vv.z; r.w = xv.w * vv.w;
        const int gc = (c >> 3) & 3;
        *reinterpret_cast<float4*>(Xs + c * 128 + (pq ^ (gc << 4))) = r;
    }
    __syncthreads();

    // --- MFMA: each wave computes [64 o][32 p] at n0 = w*32 ---
    f32x4 acc[4][2] = {};
    const int n0 = w * 32;
    const int g  = l >> 4;
    #pragma unroll
    for (int nt = 0; nt < 2; ++nt) {
        const int pl = n0 + nt * 16 + (l & 15);
        #pragma unroll
        for (int ks = 0; ks < 2; ++ks) {
            const float* col = Xs + (ks * 32 + g * 8) * 128 + (pl ^ (g << 4));
            bf16x8 bb;
            #pragma unroll
            for (int j = 0; j < 8; ++j) bb[j] = (__bf16)col[j * 128];
            #pragma unroll
            for (int mt = 0; mt < 4; ++mt)
                acc[mt][nt] = __builtin_amdgcn_mfma_f32_16x16x32_bf16(
                    A[mt][ks], bb, acc[mt][nt], 0, 0, 0);
        }
    }

    // --- Epilogue: soft-threshold + store ---
    #pragma unroll
    for (int nt = 0; nt < 2; ++nt) {
        const int p  = p0 + n0 + nt * 16 + (l & 15);
        const float Tp = fmaxf(T[p], 0.0f);
        #pragma unroll
        for (int mt = 0; mt < 4; ++mt) {
            #pragma unroll
            for (int r = 0; r < 4; ++r) {
                const int o = mt * 16 + g * 4 + r;
                float val = acc[mt][nt][r];
                float mag = fmaxf(fabsf(val) - Tp, 0.0f);
                buf[(size_t)b * 64 * HW + (size_t)o * HW + p] = copysignf(mag, val);
            }
        }
    }
}

extern "C" void kernel_launch(void* const* d_in, const int* in_sizes, int n_in,
                              void* d_out, int out_size, void* d_ws, size_t ws_size,
                              hipStream_t stream) {
    const float* x = (const float*)d_in[0];
    const float* W = (const float*)d_in[1];
    const float* v = (const float*)d_in[2];
    const float* T = (const float*)d_in[3];
    float* out = (float*)d_out;

    // f2 = WHT2D(x) -> d_out
    k_wht2d_fwd<<<NPLANE, 256, 0, stream>>>(x, out);
    // f6 = soft_threshold(W @ (v .* f2), T) -> d_out (in place)
    k_mix_mfma<<<32 * 128, 256, 0, stream>>>(out, W, v, T);
    // y = WHT2D(f6)/16384 + x -> d_out (in place)
    k_wht2d_inv<<<NPLANE, 256, 0, stream>>>(out, x);
}